// Round 5
// baseline (27521.097 us; speedup 1.0000x reference)
//
#include <hip/hip_runtime.h>
#include <cstdint>
#include <cstddef>

// ---------------------------------------------------------------------------
// 2-layer LSTM sampler, BATCH=2048, 100 steps, exact jax.random.categorical
// reproduction (threefry2x32, partitionable bits). Round-5: round-4's
// live-row compaction with the crash fixed — the live list is now PADDED to
// BATCH with row 0 (round 4 read the 0xAA-poisoned tail for slots >= L,
// producing wild addresses -> GPU fault). Pad slots do valid dummy reads of
// row 0; all writes remain guarded by slot < L.
// ---------------------------------------------------------------------------

constexpr int PAD_TOK = 0, BOS_TOK = 1, EOS_TOK = 2;
constexpr int VOCAB = 32, EMB = 64, HID = 1024, BATCH = 2048, MAXLEN = 100;
constexpr int BM = 128, BK = 32;      // N-tile = 128 = 4 gates x 32 units
constexpr float SCALE = 64.0f;        // fp16-split scale (keeps lo normal)
constexpr double INV_S2 = 1.0 / 4096.0;

using half8 = __attribute__((ext_vector_type(8))) _Float16;
using f32x4 = __attribute__((ext_vector_type(4))) float;
typedef unsigned short u16;
typedef uint32_t u32;

__device__ __forceinline__ u32 rotl32(u32 v, int d) {
  return (v << d) | (v >> (32 - d));
}

__device__ __forceinline__ void threefry2x32(u32 k0, u32 k1, u32 x0, u32 x1,
                                             u32& y0, u32& y1) {
  const u32 k2 = k0 ^ k1 ^ 0x1BD11BDAu;
#define TF_ROUND(r) do { x0 += x1; x1 = rotl32(x1, (r)); x1 ^= x0; } while (0)
  x0 += k0; x1 += k1;
  TF_ROUND(13); TF_ROUND(15); TF_ROUND(26); TF_ROUND(6);
  x0 += k1; x1 += k2 + 1u;
  TF_ROUND(17); TF_ROUND(29); TF_ROUND(16); TF_ROUND(24);
  x0 += k2; x1 += k0 + 2u;
  TF_ROUND(13); TF_ROUND(15); TF_ROUND(26); TF_ROUND(6);
  x0 += k0; x1 += k1 + 3u;
  TF_ROUND(17); TF_ROUND(29); TF_ROUND(16); TF_ROUND(24);
  x0 += k1; x1 += k2 + 4u;
  TF_ROUND(13); TF_ROUND(15); TF_ROUND(26); TF_ROUND(6);
  x0 += k2; x1 += k0 + 5u;
#undef TF_ROUND
  y0 = x0; y1 = x1;
}

// async global->LDS, 16 bytes per lane; LDS dest is wave-uniform base,
// GLOBAL source is per-lane (so row indirection is free here).
__device__ __forceinline__ void gl_lds16(const void* g, void* l) {
  __builtin_amdgcn_global_load_lds(
      (const __attribute__((address_space(1))) void*)g,
      (__attribute__((address_space(3))) void*)l, 16, 0, 0);
}

// ---------------------------------------------------------------------------
// fp16 hi/lo split of a f32 array, scaled by 64.
// ---------------------------------------------------------------------------
__global__ __launch_bounds__(256) void split_kernel(
    const float* __restrict__ src, u16* __restrict__ hi, u16* __restrict__ lo,
    int n) {
  const int i = blockIdx.x * 256 + threadIdx.x;
  if (i >= n) return;
  const float x = src[i] * SCALE;
  const _Float16 h = (_Float16)x;
  const float rem = x - (float)h;
  const _Float16 l = (_Float16)rem;
  hi[i] = __builtin_bit_cast(u16, h);
  lo[i] = __builtin_bit_cast(u16, l);
}

// ---------------------------------------------------------------------------
__global__ __launch_bounds__(256) void init_kernel(
    const int* __restrict__ prevs, float* __restrict__ c0,
    float* __restrict__ c1, u16* __restrict__ h0hi0, u16* __restrict__ h0lo0,
    u16* __restrict__ h0hi1, u16* __restrict__ h0lo1,
    u16* __restrict__ h1hi0, u16* __restrict__ h1lo0,
    u16* __restrict__ h1hi1, u16* __restrict__ h1lo1,
    int* __restrict__ prev, int* __restrict__ is_end,
    int* __restrict__ lengths, u32* __restrict__ keys,
    int* __restrict__ out_tok, int* __restrict__ live0,
    int* __restrict__ cnt0) {
  const int tid = blockIdx.x * 256 + threadIdx.x;
  const int total = BATCH * HID;
  if (tid < total) {
    c0[tid] = 0.0f; c1[tid] = 0.0f;
    h0hi0[tid] = 0; h0lo0[tid] = 0; h0hi1[tid] = 0; h0lo1[tid] = 0;
    h1hi0[tid] = 0; h1lo0[tid] = 0; h1hi1[tid] = 0; h1lo1[tid] = 0;
  }
  // pre-fill all token slots: col 0 = BOS(prevs), rest = PAD (dead rows keep
  // PAD; live rows get overwritten by the sampler each step)
  if (tid < BATCH * (MAXLEN + 1)) {
    out_tok[tid] =
        (tid % (MAXLEN + 1) == 0) ? prevs[tid / (MAXLEN + 1)] : PAD_TOK;
  }
  if (tid < BATCH) {
    const int p = prevs[tid];
    prev[tid] = p;
    is_end[tid] = (p == EOS_TOK) ? 1 : 0;
    lengths[tid] = 0;
    live0[tid] = tid;  // identity live list
  }
  if (tid < MAXLEN) {
    u32 y0, y1;
    threefry2x32(0u, 42u, 0u, (u32)tid, y0, y1);
    keys[2 * tid] = y0;
    keys[2 * tid + 1] = y1;
  }
  if (tid == 0) cnt0[0] = BATCH;
}

// ---------------------------------------------------------------------------
// Order-preserving live-list compaction: liveB = [r in liveA : !is_end[r]],
// then PAD the tail liveB[base..BATCH) with row 0 so downstream kernels can
// safely dereference any slot (writes stay guarded by slot < cnt).
// One block, 1024 threads, 2 phases of 1024 slots; ballot + wave prefix.
// ---------------------------------------------------------------------------
__global__ __launch_bounds__(1024) void compact_kernel(
    const int* __restrict__ liveA, const int* __restrict__ cntA,
    const int* __restrict__ is_end, int* __restrict__ liveB,
    int* __restrict__ cntB) {
  __shared__ int wcnt[16];
  const int tid = threadIdx.x;
  const int wid = tid >> 6, lane = tid & 63;
  const int L = cntA[0];
  int base = 0;
#pragma unroll
  for (int ph = 0; ph < 2; ++ph) {
    const int slot = ph * 1024 + tid;
    const int r = (slot < L) ? liveA[slot] : 0;
    const bool keep = (slot < L) && (is_end[r] == 0);
    const unsigned long long m = __ballot(keep);
    if (lane == 0) wcnt[wid] = __popcll(m);
    __syncthreads();
    int woff = 0, tot = 0;
#pragma unroll
    for (int w = 0; w < 16; ++w) {
      const int c = wcnt[w];
      if (w < wid) woff += c;
      tot += c;
    }
    if (keep) {
      const int pos =
          base + woff + __popcll(m & ((1ull << lane) - 1ull));
      liveB[pos] = r;
    }
    base += tot;
    __syncthreads();
  }
  // pad tail with a safe physical row (0): pad slots only ever do dummy READS
  for (int s = base + tid; s < BATCH; s += 1024) liveB[s] = 0;
  if (tid == 0) cntB[0] = base;
}

// ---------------------------------------------------------------------------
// MFMA LSTM layer over the COMPACTED row list.  gates = A0*W0^T + A1*W1^T
// (fp16x3 split, x64 scaled) then fused fp64 cell update. Row dimension is
// live-slot index; physical row = liverow[slot] (per-lane indirection on the
// global source addresses of global_load_lds).
// ---------------------------------------------------------------------------
template <bool GATHER, bool WRITE_F32>
__global__ __launch_bounds__(256) void lstm_mfma(
    const u16* __restrict__ A0hi, const u16* __restrict__ A0lo, int lda0,
    int nk0, const int* __restrict__ ptok, const u16* __restrict__ A1hi,
    const u16* __restrict__ A1lo, const u16* __restrict__ W0hi,
    const u16* __restrict__ W0lo, const u16* __restrict__ W1hi,
    const u16* __restrict__ W1lo, const float* __restrict__ bih,
    const float* __restrict__ bhh, float* __restrict__ Cst,
    float* __restrict__ Hf32, u16* __restrict__ Hhi, u16* __restrict__ Hlo,
    const int* __restrict__ liverow, const int* __restrict__ cnt) {
  __shared__ uint4 lds4[4224];  // 67584 B: 2 x 32KB stage bufs, or 128x132 f32
  char* lds = (char*)lds4;

  const int tid = threadIdx.x;
  const int lane = tid & 63;
  const int wid = tid >> 6;
  const int wm = wid >> 1, wn = wid & 1;

  // XCD swizzle keeps all mt (row tiles) present on every XCD, so shrinking
  // L idles blocks evenly across XCDs.
  const int bid = blockIdx.x;
  const int swz = (bid & 7) * 64 + (bid >> 3);
  const int ut = swz >> 4;   // 0..31 unit tile
  const int mt = swz & 15;   // 0..15 row tile
  const int u0 = ut * 32;
  const int row0 = mt * BM;

  const int L = cnt[0];
  if (row0 >= L) return;  // block-uniform exit

  // staging decode: slot = wid*64 + i*256 + lane
  const int r15 = lane & 15;
  const int kgrp = lane >> 4;  // 0..3
  int prow[2], wrow[2], tok[2];
#pragma unroll
  for (int i = 0; i < 2; ++i) {
    const int fm = wid + i * 4;
    const int slot = row0 + fm * 16 + r15;        // live-slot index (<2048)
    prow[i] = liverow[slot];                      // physical row; tail of the
                                                  // list is padded with 0, so
                                                  // always a valid row
    const int n = fm * 16 + r15;
    wrow[i] = (n >> 5) * HID + u0 + (n & 31);
  }
  if (GATHER) { tok[0] = ptok[prow[0]]; tok[1] = ptok[prow[1]]; }

  const int nk1 = HID / BK;
  const int NT = nk0 + nk1;

  auto ldso = [&](int buf, int plane, int slot) -> char* {
    return lds + buf * 32768 + plane * 8192 + slot * 16;
  };

  auto stage = [&](int buf, int kt) {
    const bool s0 = kt < nk0;
    const int kk = (s0 ? kt : kt - nk0) * BK;
    const u16* ah = s0 ? A0hi : A1hi;
    const u16* al = s0 ? A0lo : A1lo;
    const u16* wh = s0 ? W0hi : W1hi;
    const u16* wl = s0 ? W0lo : W1lo;
    const int lda = s0 ? lda0 : HID;
    const int kof = kk + kgrp * 8;
#pragma unroll
    for (int i = 0; i < 2; ++i) {
      const size_t aoff = (GATHER && s0)
                              ? ((size_t)tok[i] * lda + kof)
                              : ((size_t)prow[i] * lda + kof);
      const size_t woff = (size_t)wrow[i] * lda + kof;
      const int sbase = wid * 64 + i * 256;  // wave-uniform; +lane*16 by HW
      gl_lds16(ah + aoff, ldso(buf, 0, sbase));
      gl_lds16(al + aoff, ldso(buf, 1, sbase));
      gl_lds16(wh + woff, ldso(buf, 2, sbase));
      gl_lds16(wl + woff, ldso(buf, 3, sbase));
    }
  };

  f32x4 acc[4][4] = {};

  auto compute = [&](int buf) {
    half8 ah[4], al[4];
#pragma unroll
    for (int mi = 0; mi < 4; ++mi) {
      ah[mi] = *(const half8*)ldso(buf, 0, (wm * 4 + mi) * 64 + lane);
      al[mi] = *(const half8*)ldso(buf, 1, (wm * 4 + mi) * 64 + lane);
    }
#pragma unroll
    for (int ni = 0; ni < 4; ++ni) {
      const half8 bh = *(const half8*)ldso(buf, 2, (wn * 4 + ni) * 64 + lane);
      const half8 bl = *(const half8*)ldso(buf, 3, (wn * 4 + ni) * 64 + lane);
#pragma unroll
      for (int mi = 0; mi < 4; ++mi) {
        acc[mi][ni] =
            __builtin_amdgcn_mfma_f32_16x16x32_f16(ah[mi], bh, acc[mi][ni], 0, 0, 0);
        acc[mi][ni] =
            __builtin_amdgcn_mfma_f32_16x16x32_f16(ah[mi], bl, acc[mi][ni], 0, 0, 0);
        acc[mi][ni] =
            __builtin_amdgcn_mfma_f32_16x16x32_f16(al[mi], bh, acc[mi][ni], 0, 0, 0);
      }
    }
  };

  stage(0, 0);
  __syncthreads();  // drains vmcnt -> buf0 ready
#pragma unroll 1
  for (int t = 0; t < NT; ++t) {
    if (t + 1 < NT) stage((t + 1) & 1, t + 1);  // fly under compute(t)
    compute(t & 1);
    __syncthreads();  // drain t+1 loads + protect buf reuse
  }

  // ---- epilogue: exchange C through LDS, fp64 cell update ----
  float* cb = (float*)lds;  // [128][132]
#pragma unroll
  for (int mi = 0; mi < 4; ++mi)
#pragma unroll
    for (int ni = 0; ni < 4; ++ni) {
      const int col = wn * 64 + ni * 16 + (lane & 15);
      const int rb = wm * 64 + mi * 16 + ((lane >> 4) << 2);
#pragma unroll
      for (int r = 0; r < 4; ++r) cb[(rb + r) * 132 + col] = acc[mi][ni][r];
    }
  __syncthreads();

#pragma unroll 1
  for (int i = 0; i < 16; ++i) {
    const int idx = tid + i * 256;
    const int r = idx >> 5, ui = idx & 31;
    const int slot = row0 + r;
    if (slot >= L) continue;               // padding slots: discard
    const int grow = liverow[slot];        // physical row
    const int u = u0 + ui;
    const float* cr = cb + r * 132 + ui;
    const double gI = (double)cr[0]  * INV_S2 + (double)bih[u]           + (double)bhh[u];
    const double gF = (double)cr[32] * INV_S2 + (double)bih[HID + u]     + (double)bhh[HID + u];
    const double gG = (double)cr[64] * INV_S2 + (double)bih[2 * HID + u] + (double)bhh[2 * HID + u];
    const double gO = (double)cr[96] * INV_S2 + (double)bih[3 * HID + u] + (double)bhh[3 * HID + u];
    const double ii = 1.0 / (1.0 + exp(-gI));
    const double ff = 1.0 / (1.0 + exp(-gF));
    const double gt = tanh(gG);
    const double oo = 1.0 / (1.0 + exp(-gO));
    const size_t off = (size_t)grow * HID + u;
    const double cn = ff * (double)Cst[off] + ii * gt;
    Cst[off] = (float)cn;
    const float hf = (float)(oo * tanh(cn));
    if (WRITE_F32) Hf32[off] = hf;
    const float hs = hf * SCALE;
    const _Float16 hh = (_Float16)hs;
    const float rem = hs - (float)hh;
    const _Float16 hl = (_Float16)rem;
    Hhi[off] = __builtin_bit_cast(u16, hh);
    Hlo[off] = __builtin_bit_cast(u16, hl);
  }
}

// ---------------------------------------------------------------------------
// Logits + gumbel + argmax over live rows only (rows in the list have
// is_end==0 by construction). PRNG counter uses the PHYSICAL row index.
// ---------------------------------------------------------------------------
__global__ __launch_bounds__(256) void sample_kernel(
    const float* __restrict__ h1, const float* __restrict__ Wout,
    const float* __restrict__ bout, const u32* __restrict__ keys, int t,
    int* __restrict__ prev, int* __restrict__ is_end, int* __restrict__ lengths,
    int* __restrict__ out_tok, int* __restrict__ len_out,
    const int* __restrict__ liverow, const int* __restrict__ cnt) {
  const int wave = threadIdx.x >> 6;
  const int lane = threadIdx.x & 63;
  const int slot = blockIdx.x * 4 + wave;
  const int L = cnt[0];
  if (slot >= L) return;  // wave-uniform exit (no syncthreads in kernel)
  const int row = liverow[slot];
  const int v = lane & 31;
  const int half = lane >> 5;

  const float* hseg = h1 + (size_t)row * HID + half * (HID / 2);
  const float* wseg = Wout + (size_t)v * HID + half * (HID / 2);

  double acc = 0.0;
#pragma unroll 4
  for (int k = 0; k < HID / 2; k += 4) {
    const float4 w = *(const float4*)(wseg + k);
    const float4 h = *(const float4*)(hseg + k);
    acc = fma((double)w.x, (double)h.x, acc);
    acc = fma((double)w.y, (double)h.y, acc);
    acc = fma((double)w.z, (double)h.z, acc);
    acc = fma((double)w.w, (double)h.w, acc);
  }
  acc += __shfl_xor(acc, 32);

  const u32 k0 = keys[2 * t], k1 = keys[2 * t + 1];
  u32 y0, y1;
  threefry2x32(k0, k1, 0u, (u32)(row * VOCAB + v), y0, y1);
  const u32 bits = y0 ^ y1;
  const float f = __uint_as_float((bits >> 9) | 0x3f800000u) - 1.0f;
  const float uu = fmaxf(f, 1.17549435e-38f);
  const double g = -log(-log((double)uu));

  double z = acc + (double)bout[v] + g;
  int idx = v;
#pragma unroll
  for (int m = 1; m < 32; m <<= 1) {
    const double zo = __shfl_xor(z, m);
    const int io = __shfl_xor(idx, m);
    if (zo > z || (zo == z && io < idx)) { z = zo; idx = io; }
  }

  if (lane == 0) {
    const int cur = idx;                      // row is live: is_end==0
    const int len = lengths[row] + 1;
    const bool fin = (cur == EOS_TOK);
    prev[row] = cur;
    is_end[row] = fin ? 1 : 0;
    lengths[row] = len;
    out_tok[(size_t)row * (MAXLEN + 1) + t + 1] = cur;
    if (fin || t == MAXLEN - 1) len_out[row] = len + 1;  // +1 for BOS
  }
}

// ---------------------------------------------------------------------------
extern "C" void kernel_launch(void* const* d_in, const int* in_sizes, int n_in,
                              void* d_out, int out_size, void* d_ws,
                              size_t ws_size, hipStream_t stream) {
  const int* prevs = (const int*)d_in[0];
  const float* emb = (const float*)d_in[1];
  const float* Wih0 = (const float*)d_in[2];
  const float* Whh0 = (const float*)d_in[3];
  const float* bih0 = (const float*)d_in[4];
  const float* bhh0 = (const float*)d_in[5];
  const float* Wih1 = (const float*)d_in[6];
  const float* Whh1 = (const float*)d_in[7];
  const float* bih1 = (const float*)d_in[8];
  const float* bhh1 = (const float*)d_in[9];
  const float* Wout = (const float*)d_in[10];
  const float* bout = (const float*)d_in[11];

  const size_t SH = (size_t)BATCH * HID;        // 2M elements
  const size_t SW = (size_t)(4 * HID) * HID;    // 4M elements
  const size_t SW0 = (size_t)(4 * HID) * EMB;   // 256K elements

  float* c0 = (float*)d_ws;
  float* c1 = c0 + SH;
  float* h1f = c1 + SH;
  u16* u = (u16*)(h1f + SH);
  u16* h0hi[2] = {u, u + SH};
  u16* h0lo[2] = {u + 2 * SH, u + 3 * SH};
  u16* h1hi[2] = {u + 4 * SH, u + 5 * SH};
  u16* h1lo[2] = {u + 6 * SH, u + 7 * SH};
  u16* wp = u + 8 * SH;
  u16* wih0hi = wp;            u16* wih0lo = wp + SW0;
  u16* whh0hi = wp + 2 * SW0;  u16* whh0lo = whh0hi + SW;
  u16* wih1hi = whh0lo + SW;   u16* wih1lo = wih1hi + SW;
  u16* whh1hi = wih1lo + SW;   u16* whh1lo = whh1hi + SW;
  u16* embhi = whh1lo + SW;    u16* emblo = embhi + VOCAB * EMB;
  int* prev = (int*)(emblo + VOCAB * EMB);
  int* is_end = prev + BATCH;
  int* lengths = is_end + BATCH;
  u32* keys = (u32*)(lengths + BATCH);
  int* live0 = (int*)(keys + 2 * MAXLEN);
  int* live1 = live0 + BATCH;
  int* cnt0 = live1 + BATCH;
  int* cnt1 = cnt0 + 1;
  // total ~106 MB

  int* out_tok = (int*)d_out;
  int* len_out = out_tok + (size_t)BATCH * (MAXLEN + 1);

  init_kernel<<<dim3((BATCH * HID) / 256), 256, 0, stream>>>(
      prevs, c0, c1, h0hi[0], h0lo[0], h0hi[1], h0lo[1], h1hi[0], h1lo[0],
      h1hi[1], h1lo[1], prev, is_end, lengths, keys, out_tok, live0, cnt0);

  split_kernel<<<dim3((int)((SW0 + 255) / 256)), 256, 0, stream>>>(Wih0, wih0hi, wih0lo, (int)SW0);
  split_kernel<<<dim3((int)((SW + 255) / 256)), 256, 0, stream>>>(Whh0, whh0hi, whh0lo, (int)SW);
  split_kernel<<<dim3((int)((SW + 255) / 256)), 256, 0, stream>>>(Wih1, wih1hi, wih1lo, (int)SW);
  split_kernel<<<dim3((int)((SW + 255) / 256)), 256, 0, stream>>>(Whh1, whh1hi, whh1lo, (int)SW);
  split_kernel<<<dim3((VOCAB * EMB + 255) / 256), 256, 0, stream>>>(emb, embhi, emblo, VOCAB * EMB);

  int* live[2] = {live0, live1};
  int* cnt[2] = {cnt0, cnt1};
  int p = 0;
  for (int t = 0; t < MAXLEN; ++t) {
    const int a = t & 1, b = a ^ 1;
    lstm_mfma<true, false><<<dim3(512), 256, 0, stream>>>(
        embhi, emblo, EMB, EMB / BK, prev, h0hi[p], h0lo[p], wih0hi, wih0lo,
        whh0hi, whh0lo, bih0, bhh0, c0, nullptr, h0hi[p ^ 1], h0lo[p ^ 1],
        live[a], cnt[a]);
    lstm_mfma<false, true><<<dim3(512), 256, 0, stream>>>(
        h0hi[p ^ 1], h0lo[p ^ 1], HID, HID / BK, nullptr, h1hi[p], h1lo[p],
        wih1hi, wih1lo, whh1hi, whh1lo, bih1, bhh1, c1, h1f, h1hi[p ^ 1],
        h1lo[p ^ 1], live[a], cnt[a]);
    sample_kernel<<<dim3(BATCH / 4), 256, 0, stream>>>(
        h1f, Wout, bout, keys, t, prev, is_end, lengths, out_tok, len_out,
        live[a], cnt[a]);
    if (t + 1 < MAXLEN) {
      compact_kernel<<<dim3(1), 1024, 0, stream>>>(live[a], cnt[a], is_end,
                                                   live[b], cnt[b]);
    }
    p ^= 1;
  }
  (void)in_sizes; (void)n_in; (void)out_size; (void)ws_size;
}

// Round 6
// 26185.770 us; speedup vs baseline: 1.0510x; 1.0510x over previous
//
#include <hip/hip_runtime.h>
#include <cstdint>
#include <cstddef>

// ---------------------------------------------------------------------------
// 2-layer LSTM sampler, BATCH=2048, 100 steps, exact jax.random.categorical
// reproduction (threefry2x32, partitionable bits). Round-6: COALESCED
// staging. Round-5 showed per-step time is L-independent -> k-loop is bound
// by scattered per-lane gathers (each gl_lds16 hit 64 distinct 2KB-strided
// rows = 64 transactions) draining at the per-iter vmcnt(0) barrier. Now all
// GEMM operands are pre-packed in fragment order ([tile][ktile][slot][8]
// halfwords), so every gl_lds16 reads lane-consecutive 16B (1KB contiguous
// per instruction). Weights packed once at launch (fused split+pack); h
// states written packed by the producing epilogue. Compaction dropped (zero
// benefit). Math identical to rounds 2-5 (absmax 0.0 proven).
// ---------------------------------------------------------------------------

constexpr int PAD_TOK = 0, BOS_TOK = 1, EOS_TOK = 2;
constexpr int VOCAB = 32, EMB = 64, HID = 1024, BATCH = 2048, MAXLEN = 100;
constexpr int BK = 32;               // k-tile depth (halfwords)
constexpr int NKT_H = HID / BK;      // 32 k-tiles for K=1024
constexpr float SCALE = 64.0f;       // fp16-split scale (keeps lo normal)
constexpr double INV_S2 = 1.0 / 4096.0;

using half8 = __attribute__((ext_vector_type(8))) _Float16;
using f32x4 = __attribute__((ext_vector_type(4))) float;
typedef unsigned short u16;
typedef uint32_t u32;

__device__ __forceinline__ u32 rotl32(u32 v, int d) {
  return (v << d) | (v >> (32 - d));
}

__device__ __forceinline__ void threefry2x32(u32 k0, u32 k1, u32 x0, u32 x1,
                                             u32& y0, u32& y1) {
  const u32 k2 = k0 ^ k1 ^ 0x1BD11BDAu;
#define TF_ROUND(r) do { x0 += x1; x1 = rotl32(x1, (r)); x1 ^= x0; } while (0)
  x0 += k0; x1 += k1;
  TF_ROUND(13); TF_ROUND(15); TF_ROUND(26); TF_ROUND(6);
  x0 += k1; x1 += k2 + 1u;
  TF_ROUND(17); TF_ROUND(29); TF_ROUND(16); TF_ROUND(24);
  x0 += k2; x1 += k0 + 2u;
  TF_ROUND(13); TF_ROUND(15); TF_ROUND(26); TF_ROUND(6);
  x0 += k0; x1 += k1 + 3u;
  TF_ROUND(17); TF_ROUND(29); TF_ROUND(16); TF_ROUND(24);
  x0 += k1; x1 += k2 + 4u;
  TF_ROUND(13); TF_ROUND(15); TF_ROUND(26); TF_ROUND(6);
  x0 += k2; x1 += k0 + 5u;
#undef TF_ROUND
  y0 = x0; y1 = x1;
}

// async global->LDS, 16 bytes per lane; LDS dest = wave-uniform base + lane*16
__device__ __forceinline__ void gl_lds16(const void* g, void* l) {
  __builtin_amdgcn_global_load_lds(
      (const __attribute__((address_space(1))) void*)g,
      (__attribute__((address_space(3))) void*)l, 16, 0, 0);
}

// ---------------------------------------------------------------------------
// Fused fp16 split + fragment-order pack for one weight matrix [4H x K].
// Packed image: chunk[(ut*nkt + kt)*512 + slot] (uint4 = 8 halfwords), where
// slot = fm*64 + kgrp*16 + r15 and element e of the chunk is
//   W[(n>>5)*HID + ut*32 + (n&31)][kt*32 + kgrp*8 + e],  n = fm*16 + r15.
// This is exactly the LDS image the GEMM consumes -> staging is a pure copy.
// ---------------------------------------------------------------------------
__global__ __launch_bounds__(256) void pack_w(
    const float* __restrict__ src, int K, int nkt,
    uint4* __restrict__ dhi, uint4* __restrict__ dlo, int nchunks) {
  const int g = blockIdx.x * 256 + threadIdx.x;
  if (g >= nchunks) return;
  const int ut = g / (nkt * 512);
  const int rem = g - ut * (nkt * 512);
  const int kt = rem >> 9;
  const int slot = rem & 511;
  const int fm = slot >> 6, kg = (slot >> 4) & 3, r15 = slot & 15;
  const int n = fm * 16 + r15;
  const int row = (n >> 5) * HID + ut * 32 + (n & 31);
  const int col = kt * 32 + kg * 8;
  const float* s = src + (size_t)row * K + col;
  u16 hh[8], ll[8];
#pragma unroll
  for (int e = 0; e < 8; ++e) {
    const float x = s[e] * SCALE;
    const _Float16 h = (_Float16)x;
    const float rm = x - (float)h;
    const _Float16 l = (_Float16)rm;
    hh[e] = __builtin_bit_cast(u16, h);
    ll[e] = __builtin_bit_cast(u16, l);
  }
  dhi[g] = make_uint4((u32)hh[0] | ((u32)hh[1] << 16),
                      (u32)hh[2] | ((u32)hh[3] << 16),
                      (u32)hh[4] | ((u32)hh[5] << 16),
                      (u32)hh[6] | ((u32)hh[7] << 16));
  dlo[g] = make_uint4((u32)ll[0] | ((u32)ll[1] << 16),
                      (u32)ll[2] | ((u32)ll[3] << 16),
                      (u32)ll[4] | ((u32)ll[5] << 16),
                      (u32)ll[6] | ((u32)ll[7] << 16));
}

// ---------------------------------------------------------------------------
// fp16 hi/lo split of a f32 array (row-major, used for emb only).
// ---------------------------------------------------------------------------
__global__ __launch_bounds__(256) void split_kernel(
    const float* __restrict__ src, u16* __restrict__ hi, u16* __restrict__ lo,
    int n) {
  const int i = blockIdx.x * 256 + threadIdx.x;
  if (i >= n) return;
  const float x = src[i] * SCALE;
  const _Float16 h = (_Float16)x;
  const float rem = x - (float)h;
  const _Float16 l = (_Float16)rem;
  hi[i] = __builtin_bit_cast(u16, h);
  lo[i] = __builtin_bit_cast(u16, l);
}

// ---------------------------------------------------------------------------
__global__ __launch_bounds__(256) void init_kernel(
    const int* __restrict__ prevs, float* __restrict__ c0,
    float* __restrict__ c1, u16* __restrict__ h0hi0, u16* __restrict__ h0lo0,
    u16* __restrict__ h0hi1, u16* __restrict__ h0lo1,
    u16* __restrict__ h1hi0, u16* __restrict__ h1lo0,
    u16* __restrict__ h1hi1, u16* __restrict__ h1lo1,
    int* __restrict__ prev, int* __restrict__ is_end,
    int* __restrict__ lengths, u32* __restrict__ keys,
    int* __restrict__ out_tok) {
  const int tid = blockIdx.x * 256 + threadIdx.x;
  const int total = BATCH * HID;
  if (tid < total) {
    c0[tid] = 0.0f; c1[tid] = 0.0f;
    h0hi0[tid] = 0; h0lo0[tid] = 0; h0hi1[tid] = 0; h0lo1[tid] = 0;
    h1hi0[tid] = 0; h1lo0[tid] = 0; h1hi1[tid] = 0; h1lo1[tid] = 0;
  }
  if (tid < BATCH) {
    const int p = prevs[tid];
    prev[tid] = p;
    is_end[tid] = (p == EOS_TOK) ? 1 : 0;
    lengths[tid] = 0;
    out_tok[(size_t)tid * (MAXLEN + 1)] = p;
  }
  if (tid < MAXLEN) {
    u32 y0, y1;
    threefry2x32(0u, 42u, 0u, (u32)tid, y0, y1);
    keys[2 * tid] = y0;
    keys[2 * tid + 1] = y1;
  }
}

// ---------------------------------------------------------------------------
// MFMA LSTM layer, packed operands.  gates = A0*W0^T + A1*W1^T (fp16x3
// split, x64 scaled both sides) then fused fp64 cell update.
// Block: 128 rows x (4 gates x 32 units); 4 waves (2x2); 16x16x32 f16 MFMA.
// All staging loads are lane-consecutive 16B from packed planes (coalesced),
// except the tiny emb-gather phase (GATHER, nk0=2 k-tiles).
// Epilogue writes h hi/lo back in PACKED fragment order for the next GEMM.
// ---------------------------------------------------------------------------
template <bool GATHER, bool WRITE_F32>
__global__ __launch_bounds__(256) void lstm_mfma(
    const uint4* __restrict__ A0p_hi, const uint4* __restrict__ A0p_lo,
    const u16* __restrict__ Ehi, const u16* __restrict__ Elo,
    const int* __restrict__ ptok, int nk0,
    const uint4* __restrict__ A1p_hi, const uint4* __restrict__ A1p_lo,
    const uint4* __restrict__ W0hi, const uint4* __restrict__ W0lo,
    const uint4* __restrict__ W1hi, const uint4* __restrict__ W1lo,
    const float* __restrict__ bih, const float* __restrict__ bhh,
    float* __restrict__ Cst, float* __restrict__ Hf32,
    uint4* __restrict__ Hp_hi, uint4* __restrict__ Hp_lo) {
  __shared__ uint4 lds4[4224];  // 67584 B: 2 x 32KB stage bufs / 128x132 f32
  char* lds = (char*)lds4;

  const int tid = threadIdx.x;
  const int lane = tid & 63;
  const int wid = tid >> 6;
  const int wm = wid >> 1, wn = wid & 1;

  // XCD swizzle: 512 blocks, 64 logical per XCD.
  const int bid = blockIdx.x;
  const int swz = (bid & 7) * 64 + (bid >> 3);
  const int ut = swz >> 4;   // 0..31 unit tile (also the output k-tile index)
  const int mt = swz & 15;   // 0..15 row tile
  const int u0 = ut * 32;
  const int row0 = mt * 128;

  // emb-gather decode (phase 0 of layer 1 only)
  const int r15 = lane & 15;
  const int kgrp = lane >> 4;  // 0..3
  int tok[2];
  if (GATHER) {
#pragma unroll
    for (int i = 0; i < 2; ++i)
      tok[i] = ptok[row0 + (wid + i * 4) * 16 + r15];
  }

  const int NT = nk0 + NKT_H;

  auto ldso = [&](int buf, int plane, int slot) -> char* {
    return lds + buf * 32768 + plane * 8192 + slot * 16;
  };

  // stage one k-tile into buf: 8 gl_lds16 per wave, all lane-consecutive
  // 16B reads from packed planes (except GATHER phase-0 A).
  auto stage = [&](int buf, int kt) {
    const bool s0 = kt < nk0;
    const int ktl = s0 ? kt : kt - nk0;
    const uint4* wh = s0 ? W0hi : W1hi;
    const uint4* wl = s0 ? W0lo : W1lo;
    const int wbase = (ut * (s0 ? nk0 : NKT_H) + ktl) * 512;
    const int abase = (mt * NKT_H + ktl) * 512;
#pragma unroll
    for (int i = 0; i < 2; ++i) {
      const int sbase = wid * 64 + i * 256;  // wave-uniform LDS slot base
      // W planes: coalesced
      gl_lds16(wh + wbase + sbase + lane, ldso(buf, 2, sbase));
      gl_lds16(wl + wbase + sbase + lane, ldso(buf, 3, sbase));
      // A planes
      if (GATHER && s0) {
        const size_t aoff = (size_t)tok[i] * EMB + ktl * 32 + kgrp * 8;
        gl_lds16(Ehi + aoff, ldso(buf, 0, sbase));
        gl_lds16(Elo + aoff, ldso(buf, 1, sbase));
      } else {
        const uint4* ah = s0 ? A0p_hi : A1p_hi;
        const uint4* al = s0 ? A0p_lo : A1p_lo;
        gl_lds16(ah + abase + sbase + lane, ldso(buf, 0, sbase));
        gl_lds16(al + abase + sbase + lane, ldso(buf, 1, sbase));
      }
    }
  };

  f32x4 acc[4][4] = {};

  auto compute = [&](int buf) {
    half8 ah[4], al[4];
#pragma unroll
    for (int mi = 0; mi < 4; ++mi) {
      ah[mi] = *(const half8*)ldso(buf, 0, (wm * 4 + mi) * 64 + lane);
      al[mi] = *(const half8*)ldso(buf, 1, (wm * 4 + mi) * 64 + lane);
    }
#pragma unroll
    for (int ni = 0; ni < 4; ++ni) {
      const half8 bh = *(const half8*)ldso(buf, 2, (wn * 4 + ni) * 64 + lane);
      const half8 bl = *(const half8*)ldso(buf, 3, (wn * 4 + ni) * 64 + lane);
#pragma unroll
      for (int mi = 0; mi < 4; ++mi) {
        acc[mi][ni] =
            __builtin_amdgcn_mfma_f32_16x16x32_f16(ah[mi], bh, acc[mi][ni], 0, 0, 0);
        acc[mi][ni] =
            __builtin_amdgcn_mfma_f32_16x16x32_f16(ah[mi], bl, acc[mi][ni], 0, 0, 0);
        acc[mi][ni] =
            __builtin_amdgcn_mfma_f32_16x16x32_f16(al[mi], bh, acc[mi][ni], 0, 0, 0);
      }
    }
  };

  stage(0, 0);
  __syncthreads();  // drains vmcnt -> buf0 ready
#pragma unroll 1
  for (int t = 0; t < NT; ++t) {
    if (t + 1 < NT) stage((t + 1) & 1, t + 1);  // fly under compute(t)
    compute(t & 1);
    __syncthreads();  // drain t+1 loads + protect buf reuse
  }

  // ---- epilogue: exchange C through LDS, fp64 cell update ----
  float* cb = (float*)lds;  // [128][132]
#pragma unroll
  for (int mi = 0; mi < 4; ++mi)
#pragma unroll
    for (int ni = 0; ni < 4; ++ni) {
      const int col = wn * 64 + ni * 16 + (lane & 15);
      const int rb = wm * 64 + mi * 16 + ((lane >> 4) << 2);
#pragma unroll
      for (int r = 0; r < 4; ++r) cb[(rb + r) * 132 + col] = acc[mi][ni][r];
    }
  __syncthreads();

  // 512 chunks of 8 consecutive units: chunk g -> row r = g>>2, kgrp kg = g&3.
  // Packed-h chunk index = (mt*NKT_H + ut)*512 + slot, slot = fragment order.
  const int mtut = (mt * NKT_H + ut) * 512;
#pragma unroll 1
  for (int j = 0; j < 2; ++j) {
    const int g = tid + j * 256;
    const int r = g >> 2, kg = g & 3;
    const int grow = row0 + r;
    const int ub = kg * 8;
    const float* cr = cb + r * 132 + ub;
    const size_t off = (size_t)grow * HID + u0 + ub;
    const float4 co0 = *(const float4*)(Cst + off);
    const float4 co1 = *(const float4*)(Cst + off + 4);
    const float cold[8] = {co0.x, co0.y, co0.z, co0.w,
                           co1.x, co1.y, co1.z, co1.w};
    float cn8[8], hf8[8];
    u16 hh8[8], hl8[8];
#pragma unroll
    for (int e = 0; e < 8; ++e) {
      const int u = u0 + ub + e;
      const double gI = (double)cr[e]      * INV_S2 + (double)bih[u]           + (double)bhh[u];
      const double gF = (double)cr[32 + e] * INV_S2 + (double)bih[HID + u]     + (double)bhh[HID + u];
      const double gG = (double)cr[64 + e] * INV_S2 + (double)bih[2 * HID + u] + (double)bhh[2 * HID + u];
      const double gO = (double)cr[96 + e] * INV_S2 + (double)bih[3 * HID + u] + (double)bhh[3 * HID + u];
      const double ii = 1.0 / (1.0 + exp(-gI));
      const double ff = 1.0 / (1.0 + exp(-gF));
      const double gt = tanh(gG);
      const double oo = 1.0 / (1.0 + exp(-gO));
      const double cn = ff * (double)cold[e] + ii * gt;
      cn8[e] = (float)cn;
      const float hf = (float)(oo * tanh(cn));
      hf8[e] = hf;
      const float hs = hf * SCALE;
      const _Float16 hh = (_Float16)hs;
      const float rm = hs - (float)hh;
      hh8[e] = __builtin_bit_cast(u16, hh);
      hl8[e] = __builtin_bit_cast(u16, (_Float16)rm);
    }
    *(float4*)(Cst + off) = make_float4(cn8[0], cn8[1], cn8[2], cn8[3]);
    *(float4*)(Cst + off + 4) = make_float4(cn8[4], cn8[5], cn8[6], cn8[7]);
    if (WRITE_F32) {
      *(float4*)(Hf32 + off) = make_float4(hf8[0], hf8[1], hf8[2], hf8[3]);
      *(float4*)(Hf32 + off + 4) = make_float4(hf8[4], hf8[5], hf8[6], hf8[7]);
    }
    const int slot = (r >> 4) * 64 + kg * 16 + (r & 15);
    Hp_hi[mtut + slot] = make_uint4((u32)hh8[0] | ((u32)hh8[1] << 16),
                                    (u32)hh8[2] | ((u32)hh8[3] << 16),
                                    (u32)hh8[4] | ((u32)hh8[5] << 16),
                                    (u32)hh8[6] | ((u32)hh8[7] << 16));
    Hp_lo[mtut + slot] = make_uint4((u32)hl8[0] | ((u32)hl8[1] << 16),
                                    (u32)hl8[2] | ((u32)hl8[3] << 16),
                                    (u32)hl8[4] | ((u32)hl8[5] << 16),
                                    (u32)hl8[6] | ((u32)hl8[7] << 16));
  }
}

// ---------------------------------------------------------------------------
// Logits + gumbel + argmax + EOS bookkeeping (fp64, proven exact).
// ---------------------------------------------------------------------------
__global__ __launch_bounds__(256) void sample_kernel(
    const float* __restrict__ h1, const float* __restrict__ Wout,
    const float* __restrict__ bout, const u32* __restrict__ keys, int t,
    int* __restrict__ prev, int* __restrict__ is_end, int* __restrict__ lengths,
    int* __restrict__ out_tok, int* __restrict__ len_out) {
  const int wave = threadIdx.x >> 6;
  const int lane = threadIdx.x & 63;
  const int row = blockIdx.x * 4 + wave;
  const int v = lane & 31;
  const int half = lane >> 5;

  const float* hseg = h1 + (size_t)row * HID + half * (HID / 2);
  const float* wseg = Wout + (size_t)v * HID + half * (HID / 2);

  double acc = 0.0;
#pragma unroll 4
  for (int k = 0; k < HID / 2; k += 4) {
    const float4 w = *(const float4*)(wseg + k);
    const float4 h = *(const float4*)(hseg + k);
    acc = fma((double)w.x, (double)h.x, acc);
    acc = fma((double)w.y, (double)h.y, acc);
    acc = fma((double)w.z, (double)h.z, acc);
    acc = fma((double)w.w, (double)h.w, acc);
  }
  acc += __shfl_xor(acc, 32);

  const u32 k0 = keys[2 * t], k1 = keys[2 * t + 1];
  u32 y0, y1;
  threefry2x32(k0, k1, 0u, (u32)(row * VOCAB + v), y0, y1);
  const u32 bits = y0 ^ y1;
  const float f = __uint_as_float((bits >> 9) | 0x3f800000u) - 1.0f;
  const float uu = fmaxf(f, 1.17549435e-38f);
  const double g = -log(-log((double)uu));

  double z = acc + (double)bout[v] + g;
  int idx = v;
#pragma unroll
  for (int m = 1; m < 32; m <<= 1) {
    const double zo = __shfl_xor(z, m);
    const int io = __shfl_xor(idx, m);
    if (zo > z || (zo == z && io < idx)) { z = zo; idx = io; }
  }

  if (lane == 0) {
    const int e = is_end[row];
    const int cur = e ? PAD_TOK : idx;
    const int len = lengths[row] + (e ? 0 : 1);
    const int enew = e | (cur == EOS_TOK ? 1 : 0);
    prev[row] = cur;
    is_end[row] = enew;
    lengths[row] = len;
    out_tok[(size_t)row * (MAXLEN + 1) + t + 1] = cur;
    if (len_out) len_out[row] = len + 1;  // reference returns lengths+1 (BOS)
  }
}

// ---------------------------------------------------------------------------
extern "C" void kernel_launch(void* const* d_in, const int* in_sizes, int n_in,
                              void* d_out, int out_size, void* d_ws,
                              size_t ws_size, hipStream_t stream) {
  const int* prevs = (const int*)d_in[0];
  const float* emb = (const float*)d_in[1];
  const float* Wih0 = (const float*)d_in[2];
  const float* Whh0 = (const float*)d_in[3];
  const float* bih0 = (const float*)d_in[4];
  const float* bhh0 = (const float*)d_in[5];
  const float* Wih1 = (const float*)d_in[6];
  const float* Whh1 = (const float*)d_in[7];
  const float* bih1 = (const float*)d_in[8];
  const float* bhh1 = (const float*)d_in[9];
  const float* Wout = (const float*)d_in[10];
  const float* bout = (const float*)d_in[11];

  const size_t SH = (size_t)BATCH * HID;   // 2M elements
  const size_t CH = SH / 8;                // packed h plane: 256K uint4 chunks
  const size_t CW = (size_t)32 * NKT_H * 512;  // 512K chunks (K=1024 weights)
  const size_t CW0 = (size_t)32 * 2 * 512;     // 32K chunks (Wih0, K=64)

  float* c0 = (float*)d_ws;
  float* c1 = c0 + SH;
  float* h1f = c1 + SH;
  uint4* q = (uint4*)(h1f + SH);
  uint4* ph0hi[2] = {q, q + CH};
  uint4* ph0lo[2] = {q + 2 * CH, q + 3 * CH};
  uint4* ph1hi[2] = {q + 4 * CH, q + 5 * CH};
  uint4* ph1lo[2] = {q + 6 * CH, q + 7 * CH};
  uint4* pw = q + 8 * CH;
  uint4* pwih0h = pw;              uint4* pwih0l = pwih0h + CW0;
  uint4* pwhh0h = pwih0l + CW0;    uint4* pwhh0l = pwhh0h + CW;
  uint4* pwih1h = pwhh0l + CW;     uint4* pwih1l = pwih1h + CW;
  uint4* pwhh1h = pwih1l + CW;     uint4* pwhh1l = pwhh1h + CW;
  u16* embh = (u16*)(pwhh1l + CW);
  u16* embl = embh + VOCAB * EMB;
  int* prev = (int*)(embl + VOCAB * EMB);
  int* is_end = prev + BATCH;
  int* lengths = is_end + BATCH;
  u32* keys = (u32*)(lengths + BATCH);
  // total ~110 MB

  int* out_tok = (int*)d_out;
  int* len_out = out_tok + (size_t)BATCH * (MAXLEN + 1);

  init_kernel<<<dim3((BATCH * HID) / 256), 256, 0, stream>>>(
      prevs, c0, c1, (u16*)ph0hi[0], (u16*)ph0lo[0], (u16*)ph0hi[1],
      (u16*)ph0lo[1], (u16*)ph1hi[0], (u16*)ph1lo[0], (u16*)ph1hi[1],
      (u16*)ph1lo[1], prev, is_end, lengths, keys, out_tok);

  split_kernel<<<dim3((VOCAB * EMB + 255) / 256), 256, 0, stream>>>(
      emb, embh, embl, VOCAB * EMB);
  pack_w<<<dim3((int)((CW0 + 255) / 256)), 256, 0, stream>>>(
      Wih0, EMB, 2, pwih0h, pwih0l, (int)CW0);
  pack_w<<<dim3((int)((CW + 255) / 256)), 256, 0, stream>>>(
      Whh0, HID, NKT_H, pwhh0h, pwhh0l, (int)CW);
  pack_w<<<dim3((int)((CW + 255) / 256)), 256, 0, stream>>>(
      Wih1, HID, NKT_H, pwih1h, pwih1l, (int)CW);
  pack_w<<<dim3((int)((CW + 255) / 256)), 256, 0, stream>>>(
      Whh1, HID, NKT_H, pwhh1h, pwhh1l, (int)CW);

  int p = 0;
  for (int t = 0; t < MAXLEN; ++t) {
    lstm_mfma<true, false><<<dim3(512), 256, 0, stream>>>(
        nullptr, nullptr, embh, embl, prev, 2, ph0hi[p], ph0lo[p],
        pwih0h, pwih0l, pwhh0h, pwhh0l, bih0, bhh0, c0, nullptr,
        ph0hi[p ^ 1], ph0lo[p ^ 1]);
    lstm_mfma<false, true><<<dim3(512), 256, 0, stream>>>(
        ph0hi[p ^ 1], ph0lo[p ^ 1], nullptr, nullptr, nullptr, NKT_H,
        ph1hi[p], ph1lo[p], pwih1h, pwih1l, pwhh1h, pwhh1l, bih1, bhh1,
        c1, h1f, ph1hi[p ^ 1], ph1lo[p ^ 1]);
    sample_kernel<<<dim3(BATCH / 4), 256, 0, stream>>>(
        h1f, Wout, bout, keys, t, prev, is_end, lengths, out_tok,
        (t == MAXLEN - 1) ? len_out : nullptr);
    p ^= 1;
  }
  (void)in_sizes; (void)n_in; (void)out_size; (void)ws_size;
}

// Round 7
// 17628.065 us; speedup vs baseline: 1.5612x; 1.4855x over previous
//
#include <hip/hip_runtime.h>
#include <cstdint>
#include <cstddef>

// ---------------------------------------------------------------------------
// 2-layer LSTM sampler, BATCH=2048, 100 steps, exact jax.random.categorical
// reproduction (threefry2x32, partitionable bits). Round-7:
//  * BM=256 / 512-thr blocks / grid=256 -> exactly 1 block/CU, ONE pass
//    (rounds 3-6 ran 2 sequential passes: VGPR capped residency at 1 block).
//  * gate-interleaved W packing -> acc[mi][0..3] = (I,F,G,O) in-register;
//    the 67KB LDS C-exchange is gone.
//  * fast fp64 sigmoid/tanh (exp2 Taylor-9 + rcp32+2NR, ~1e-11 rel) replaces
//    ocml exp/tanh/div -> ~3.5x less epilogue VALU. Perturbation ~1e-11 <<
//    the standing |ours-ref| gap (~2e-6 from ref's own f32 GEMM).
// GEMM math otherwise identical (fp16x3 split, x64 scale): absmax 0.0 proven.
// ---------------------------------------------------------------------------

constexpr int PAD_TOK = 0, BOS_TOK = 1, EOS_TOK = 2;
constexpr int VOCAB = 32, EMB = 64, HID = 1024, BATCH = 2048, MAXLEN = 100;
constexpr int BK = 32;               // k-tile depth (halfwords)
constexpr int NKT_H = HID / BK;      // 32 k-tiles for K=1024
constexpr float SCALE = 64.0f;       // fp16-split scale (keeps lo normal)
constexpr double INV_S2 = 1.0 / 4096.0;

using half8 = __attribute__((ext_vector_type(8))) _Float16;
using f32x4 = __attribute__((ext_vector_type(4))) float;
typedef unsigned short u16;
typedef uint32_t u32;

__device__ __forceinline__ u32 rotl32(u32 v, int d) {
  return (v << d) | (v >> (32 - d));
}

__device__ __forceinline__ void threefry2x32(u32 k0, u32 k1, u32 x0, u32 x1,
                                             u32& y0, u32& y1) {
  const u32 k2 = k0 ^ k1 ^ 0x1BD11BDAu;
#define TF_ROUND(r) do { x0 += x1; x1 = rotl32(x1, (r)); x1 ^= x0; } while (0)
  x0 += k0; x1 += k1;
  TF_ROUND(13); TF_ROUND(15); TF_ROUND(26); TF_ROUND(6);
  x0 += k1; x1 += k2 + 1u;
  TF_ROUND(17); TF_ROUND(29); TF_ROUND(16); TF_ROUND(24);
  x0 += k2; x1 += k0 + 2u;
  TF_ROUND(13); TF_ROUND(15); TF_ROUND(26); TF_ROUND(6);
  x0 += k0; x1 += k1 + 3u;
  TF_ROUND(17); TF_ROUND(29); TF_ROUND(16); TF_ROUND(24);
  x0 += k1; x1 += k2 + 4u;
  TF_ROUND(13); TF_ROUND(15); TF_ROUND(26); TF_ROUND(6);
  x0 += k2; x1 += k0 + 5u;
#undef TF_ROUND
  y0 = x0; y1 = x1;
}

// async global->LDS, 16 bytes per lane; LDS dest = wave-uniform base + lane*16
__device__ __forceinline__ void gl_lds16(const void* g, void* l) {
  __builtin_amdgcn_global_load_lds(
      (const __attribute__((address_space(1))) void*)g,
      (__attribute__((address_space(3))) void*)l, 16, 0, 0);
}

// ---- fast fp64 transcendentals (rel err ~1e-11, way below f32 ulp) --------
__device__ __forceinline__ double rcp1p(double q) {  // 1/(1+q), q >= 0
  const double d = 1.0 + q;
  double r = (double)__builtin_amdgcn_rcpf((float)d);
  r = r * fma(-d, r, 2.0);
  r = r * fma(-d, r, 2.0);
  return r;
}
__device__ __forceinline__ double exp2d(double t) {  // 2^t, |t| < ~120
  const double n = rint(t);
  const double f = t - n;  // |f| <= 0.5
  double p = 1.0178086009239699e-07;   // ln2^9/9!
  p = fma(p, f, 1.3215542443841225e-06);
  p = fma(p, f, 1.5252733804059840e-05);
  p = fma(p, f, 1.5403530393381610e-04);
  p = fma(p, f, 1.3333558146428443e-03);
  p = fma(p, f, 9.6181291076284772e-03);
  p = fma(p, f, 5.5504108664821580e-02);
  p = fma(p, f, 2.4022650695910071e-01);
  p = fma(p, f, 6.9314718055994531e-01);
  p = fma(p, f, 1.0);
  const long long e = ((long long)(int)n + 1023) << 52;
  return p * __longlong_as_double(e);
}
__device__ __forceinline__ double sigd(double x) {   // 1/(1+e^-x)
  return rcp1p(exp2d(x * -1.4426950408889634));
}
__device__ __forceinline__ double tanhd(double x) {  // 2*sig(2x)-1
  return fma(2.0, rcp1p(exp2d(x * -2.8853900817779268)), -1.0);
}

// ---------------------------------------------------------------------------
// Fused fp16 split + fragment-order pack for one weight matrix [4H x K].
// chunk[(ut*nkt + kt)*512 + slot], slot = fm*64 + kg*16 + r15; element e:
//   W[gate*HID + ut*32 + ugrp*16 + r15][kt*32 + kg*8 + e],
//   gate = fm&3, ugrp = fm>>2   (GATE-INTERLEAVED: tile ni <-> gate).
// ---------------------------------------------------------------------------
__global__ __launch_bounds__(256) void pack_w(
    const float* __restrict__ src, int K, int nkt,
    uint4* __restrict__ dhi, uint4* __restrict__ dlo, int nchunks) {
  const int g = blockIdx.x * 256 + threadIdx.x;
  if (g >= nchunks) return;
  const int ut = g / (nkt * 512);
  const int rem = g - ut * (nkt * 512);
  const int kt = rem >> 9;
  const int slot = rem & 511;
  const int fm = slot >> 6, kg = (slot >> 4) & 3, r15 = slot & 15;
  const int row = (fm & 3) * HID + ut * 32 + (fm >> 2) * 16 + r15;
  const int col = kt * 32 + kg * 8;
  const float* s = src + (size_t)row * K + col;
  u16 hh[8], ll[8];
#pragma unroll
  for (int e = 0; e < 8; ++e) {
    const float x = s[e] * SCALE;
    const _Float16 h = (_Float16)x;
    const float rm = x - (float)h;
    const _Float16 l = (_Float16)rm;
    hh[e] = __builtin_bit_cast(u16, h);
    ll[e] = __builtin_bit_cast(u16, l);
  }
  dhi[g] = make_uint4((u32)hh[0] | ((u32)hh[1] << 16),
                      (u32)hh[2] | ((u32)hh[3] << 16),
                      (u32)hh[4] | ((u32)hh[5] << 16),
                      (u32)hh[6] | ((u32)hh[7] << 16));
  dlo[g] = make_uint4((u32)ll[0] | ((u32)ll[1] << 16),
                      (u32)ll[2] | ((u32)ll[3] << 16),
                      (u32)ll[4] | ((u32)ll[5] << 16),
                      (u32)ll[6] | ((u32)ll[7] << 16));
}

// ---------------------------------------------------------------------------
__global__ __launch_bounds__(256) void split_kernel(
    const float* __restrict__ src, u16* __restrict__ hi, u16* __restrict__ lo,
    int n) {
  const int i = blockIdx.x * 256 + threadIdx.x;
  if (i >= n) return;
  const float x = src[i] * SCALE;
  const _Float16 h = (_Float16)x;
  const float rem = x - (float)h;
  const _Float16 l = (_Float16)rem;
  hi[i] = __builtin_bit_cast(u16, h);
  lo[i] = __builtin_bit_cast(u16, l);
}

// ---------------------------------------------------------------------------
__global__ __launch_bounds__(256) void init_kernel(
    const int* __restrict__ prevs, float* __restrict__ c0,
    float* __restrict__ c1, u16* __restrict__ h0hi0, u16* __restrict__ h0lo0,
    u16* __restrict__ h0hi1, u16* __restrict__ h0lo1,
    u16* __restrict__ h1hi0, u16* __restrict__ h1lo0,
    u16* __restrict__ h1hi1, u16* __restrict__ h1lo1,
    int* __restrict__ prev, int* __restrict__ is_end,
    int* __restrict__ lengths, u32* __restrict__ keys,
    int* __restrict__ out_tok) {
  const int tid = blockIdx.x * 256 + threadIdx.x;
  const int total = BATCH * HID;
  if (tid < total) {
    c0[tid] = 0.0f; c1[tid] = 0.0f;
    h0hi0[tid] = 0; h0lo0[tid] = 0; h0hi1[tid] = 0; h0lo1[tid] = 0;
    h1hi0[tid] = 0; h1lo0[tid] = 0; h1hi1[tid] = 0; h1lo1[tid] = 0;
  }
  if (tid < BATCH) {
    const int p = prevs[tid];
    prev[tid] = p;
    is_end[tid] = (p == EOS_TOK) ? 1 : 0;
    lengths[tid] = 0;
    out_tok[(size_t)tid * (MAXLEN + 1)] = p;
  }
  if (tid < MAXLEN) {
    u32 y0, y1;
    threefry2x32(0u, 42u, 0u, (u32)tid, y0, y1);
    keys[2 * tid] = y0;
    keys[2 * tid + 1] = y1;
  }
}

// ---------------------------------------------------------------------------
// MFMA LSTM layer. 256 blocks (8 mt x 32 ut), 512 threads = 8 waves (4wm x
// 2wn), each wave 64x64 output. gates = A0*W0^T + A1*W1^T (fp16x3), fused
// fast-fp64 cell update fully in-register (gate-interleaved acc).
// LDS: 2 x 48KB stage bufs (A 2x16KB + W 2x8KB); h-pack transpose overlays.
// C state in block layout [(mt*32+ut)*256 + row]*32 + u_loc (coalesced).
// ---------------------------------------------------------------------------
template <bool GATHER, bool WRITE_F32>
__global__ __launch_bounds__(512) void lstm_mfma(
    const uint4* __restrict__ A0p_hi, const uint4* __restrict__ A0p_lo,
    const u16* __restrict__ Ehi, const u16* __restrict__ Elo,
    const int* __restrict__ ptok, int nk0,
    const uint4* __restrict__ A1p_hi, const uint4* __restrict__ A1p_lo,
    const uint4* __restrict__ W0hi, const uint4* __restrict__ W0lo,
    const uint4* __restrict__ W1hi, const uint4* __restrict__ W1lo,
    const float* __restrict__ bih, const float* __restrict__ bhh,
    float* __restrict__ Cst, float* __restrict__ Hf32,
    uint4* __restrict__ Hp_hi, uint4* __restrict__ Hp_lo) {
  __shared__ uint4 lds4[6144];  // 98304 B: 2 x 48KB stage bufs
  char* lds = (char*)lds4;

  const int tid = threadIdx.x;          // 0..511
  const int lane = tid & 63;
  const int wid = tid >> 6;             // 0..7
  const int wm = wid >> 1, wn = wid & 1;

  const int bid = blockIdx.x;           // 256 blocks
  const int swz = (bid & 7) * 32 + (bid >> 3);
  const int ut = swz >> 3;              // 0..31
  const int mt = swz & 7;               // 0..7
  const int u0 = ut * 32;
  const int row0 = mt * 256;

  const int r15 = lane & 15;
  const int kgrp = lane >> 4;           // 0..3
  int tok[2];
  if (GATHER) {
#pragma unroll
    for (int j = 0; j < 2; ++j)
      tok[j] = ptok[row0 + (j * 8 + wid) * 16 + r15];
  }

  const int NT = nk0 + NKT_H;

  // buf stride 49152; A planes @0/16384 (1024 slots), W planes @32768/40960
  auto ldsA = [&](int buf, int pl, int slot) -> char* {
    return lds + buf * 49152 + pl * 16384 + slot * 16;
  };
  auto ldsW = [&](int buf, int pl, int slot) -> char* {
    return lds + buf * 49152 + 32768 + pl * 8192 + slot * 16;
  };

  auto stage = [&](int buf, int kt) {
    const bool s0 = kt < nk0;
    const int ktl = s0 ? kt : kt - nk0;
    const uint4* wh = s0 ? W0hi : W1hi;
    const uint4* wl = s0 ? W0lo : W1lo;
    const int wbase = (ut * (s0 ? nk0 : NKT_H) + ktl) * 512;
    {
      const int sb = wid * 64;
      gl_lds16(wh + wbase + sb + lane, ldsW(buf, 0, sb));
      gl_lds16(wl + wbase + sb + lane, ldsW(buf, 1, sb));
    }
    if (GATHER && s0) {
#pragma unroll
      for (int j = 0; j < 2; ++j) {
        const int sb = j * 512 + wid * 64;
        const size_t ao = (size_t)tok[j] * EMB + ktl * 32 + kgrp * 8;
        gl_lds16(Ehi + ao, ldsA(buf, 0, sb));
        gl_lds16(Elo + ao, ldsA(buf, 1, sb));
      }
    } else {
      const uint4* ah_ = s0 ? A0p_hi : A1p_hi;
      const uint4* al_ = s0 ? A0p_lo : A1p_lo;
      const int abase = (mt * NKT_H + ktl) * 1024;
#pragma unroll
      for (int j = 0; j < 2; ++j) {
        const int sb = j * 512 + wid * 64;
        gl_lds16(ah_ + abase + sb + lane, ldsA(buf, 0, sb));
        gl_lds16(al_ + abase + sb + lane, ldsA(buf, 1, sb));
      }
    }
  };

  f32x4 acc[4][4] = {};  // acc[mi][gate]

  auto compute = [&](int buf) {
    half8 ah[4], al[4];
#pragma unroll
    for (int mi = 0; mi < 4; ++mi) {
      ah[mi] = *(const half8*)ldsA(buf, 0, (wm * 4 + mi) * 64 + lane);
      al[mi] = *(const half8*)ldsA(buf, 1, (wm * 4 + mi) * 64 + lane);
    }
#pragma unroll
    for (int ni = 0; ni < 4; ++ni) {
      const half8 bh = *(const half8*)ldsW(buf, 0, (wn * 4 + ni) * 64 + lane);
      const half8 bl = *(const half8*)ldsW(buf, 1, (wn * 4 + ni) * 64 + lane);
#pragma unroll
      for (int mi = 0; mi < 4; ++mi) {
        acc[mi][ni] =
            __builtin_amdgcn_mfma_f32_16x16x32_f16(ah[mi], bh, acc[mi][ni], 0, 0, 0);
        acc[mi][ni] =
            __builtin_amdgcn_mfma_f32_16x16x32_f16(ah[mi], bl, acc[mi][ni], 0, 0, 0);
        acc[mi][ni] =
            __builtin_amdgcn_mfma_f32_16x16x32_f16(al[mi], bh, acc[mi][ni], 0, 0, 0);
      }
    }
  };

  stage(0, 0);
  __syncthreads();
#pragma unroll 1
  for (int t = 0; t < NT; ++t) {
    if (t + 1 < NT) stage((t + 1) & 1, t + 1);  // fly under compute(t)
    compute(t & 1);
    __syncthreads();
  }

  // ---- epilogue: in-register fast-fp64 cell update -------------------------
  const int u_loc = wn * 16 + r15;      // 0..31
  const int u = u0 + u_loc;
  double bsum[4];
#pragma unroll
  for (int g = 0; g < 4; ++g)
    bsum[g] = (double)bih[g * HID + u] + (double)bhh[g * HID + u];

  float* Cb = Cst + (size_t)(mt * 32 + ut) * 8192;  // [256 rows][32 units]
  u16* hhT = (u16*)lds;                 // [256][40] u16 (20KB), buf0 free
  u16* hlT = (u16*)(lds + 20480);       // [256][40] u16
  const int hi4 = lane >> 4;

#pragma unroll
  for (int mi = 0; mi < 4; ++mi) {
#pragma unroll
    for (int r = 0; r < 4; ++r) {
      const int row = wm * 64 + mi * 16 + hi4 * 4 + r;
      const double gI = (double)acc[mi][0][r] * INV_S2 + bsum[0];
      const double gF = (double)acc[mi][1][r] * INV_S2 + bsum[1];
      const double gG = (double)acc[mi][2][r] * INV_S2 + bsum[2];
      const double gO = (double)acc[mi][3][r] * INV_S2 + bsum[3];
      const double ii = sigd(gI);
      const double ff = sigd(gF);
      const double gt = tanhd(gG);
      const double oo = sigd(gO);
      const int co = row * 32 + u_loc;
      const double cn = ff * (double)Cb[co] + ii * gt;
      Cb[co] = (float)cn;
      const float hf = (float)(oo * tanhd(cn));
      if (WRITE_F32) Hf32[(size_t)(row0 + row) * HID + u] = hf;
      const float hs = hf * SCALE;
      const _Float16 hh = (_Float16)hs;
      const float rm = hs - (float)hh;
      const _Float16 hl = (_Float16)rm;
      hhT[row * 40 + u_loc] = __builtin_bit_cast(u16, hh);
      hlT[row * 40 + u_loc] = __builtin_bit_cast(u16, hl);
    }
  }
  __syncthreads();

  // pack h hi/lo planes: 1024 chunks, 2 per thread, coalesced global stores
  const size_t mtut = ((size_t)mt * NKT_H + ut) * 1024;
#pragma unroll
  for (int j = 0; j < 2; ++j) {
    const int g = tid + j * 512;
    const int fA = g >> 6, kg = (g >> 4) & 3, rr = g & 15;
    const int row = fA * 16 + rr;
    const uint4 vh = *(const uint4*)(hhT + row * 40 + kg * 8);
    const uint4 vl = *(const uint4*)(hlT + row * 40 + kg * 8);
    Hp_hi[mtut + g] = vh;
    Hp_lo[mtut + g] = vl;
  }
}

// ---------------------------------------------------------------------------
// Logits + gumbel + argmax + EOS bookkeeping (fp64, proven exact).
// ---------------------------------------------------------------------------
__global__ __launch_bounds__(256) void sample_kernel(
    const float* __restrict__ h1, const float* __restrict__ Wout,
    const float* __restrict__ bout, const u32* __restrict__ keys, int t,
    int* __restrict__ prev, int* __restrict__ is_end, int* __restrict__ lengths,
    int* __restrict__ out_tok, int* __restrict__ len_out) {
  const int wave = threadIdx.x >> 6;
  const int lane = threadIdx.x & 63;
  const int row = blockIdx.x * 4 + wave;
  const int v = lane & 31;
  const int half = lane >> 5;

  const float* hseg = h1 + (size_t)row * HID + half * (HID / 2);
  const float* wseg = Wout + (size_t)v * HID + half * (HID / 2);

  double acc = 0.0;
#pragma unroll 4
  for (int k = 0; k < HID / 2; k += 4) {
    const float4 w = *(const float4*)(wseg + k);
    const float4 h = *(const float4*)(hseg + k);
    acc = fma((double)w.x, (double)h.x, acc);
    acc = fma((double)w.y, (double)h.y, acc);
    acc = fma((double)w.z, (double)h.z, acc);
    acc = fma((double)w.w, (double)h.w, acc);
  }
  acc += __shfl_xor(acc, 32);

  const u32 k0 = keys[2 * t], k1 = keys[2 * t + 1];
  u32 y0, y1;
  threefry2x32(k0, k1, 0u, (u32)(row * VOCAB + v), y0, y1);
  const u32 bits = y0 ^ y1;
  const float f = __uint_as_float((bits >> 9) | 0x3f800000u) - 1.0f;
  const float uu = fmaxf(f, 1.17549435e-38f);
  const double g = -log(-log((double)uu));

  double z = acc + (double)bout[v] + g;
  int idx = v;
#pragma unroll
  for (int m = 1; m < 32; m <<= 1) {
    const double zo = __shfl_xor(z, m);
    const int io = __shfl_xor(idx, m);
    if (zo > z || (zo == z && io < idx)) { z = zo; idx = io; }
  }

  if (lane == 0) {
    const int e = is_end[row];
    const int cur = e ? PAD_TOK : idx;
    const int len = lengths[row] + (e ? 0 : 1);
    const int enew = e | (cur == EOS_TOK ? 1 : 0);
    prev[row] = cur;
    is_end[row] = enew;
    lengths[row] = len;
    out_tok[(size_t)row * (MAXLEN + 1) + t + 1] = cur;
    if (len_out) len_out[row] = len + 1;  // reference returns lengths+1 (BOS)
  }
}

// ---------------------------------------------------------------------------
extern "C" void kernel_launch(void* const* d_in, const int* in_sizes, int n_in,
                              void* d_out, int out_size, void* d_ws,
                              size_t ws_size, hipStream_t stream) {
  const int* prevs = (const int*)d_in[0];
  const float* emb = (const float*)d_in[1];
  const float* Wih0 = (const float*)d_in[2];
  const float* Whh0 = (const float*)d_in[3];
  const float* bih0 = (const float*)d_in[4];
  const float* bhh0 = (const float*)d_in[5];
  const float* Wih1 = (const float*)d_in[6];
  const float* Whh1 = (const float*)d_in[7];
  const float* bih1 = (const float*)d_in[8];
  const float* bhh1 = (const float*)d_in[9];
  const float* Wout = (const float*)d_in[10];
  const float* bout = (const float*)d_in[11];

  const size_t SH = (size_t)BATCH * HID;       // 2M elements
  const size_t CH = SH / 8;                    // 262144 uint4 per h plane
  const size_t CW = (size_t)32 * NKT_H * 512;  // 524288 chunks (K=1024)
  const size_t CW0 = (size_t)32 * 2 * 512;     // 32768 chunks (Wih0, K=64)

  float* c0 = (float*)d_ws;                    // block layout [mt*32+ut][256][32]
  float* c1 = c0 + SH;
  float* h1f = c1 + SH;
  uint4* q = (uint4*)(h1f + SH);
  uint4* ph0hi[2] = {q, q + CH};
  uint4* ph0lo[2] = {q + 2 * CH, q + 3 * CH};
  uint4* ph1hi[2] = {q + 4 * CH, q + 5 * CH};
  uint4* ph1lo[2] = {q + 6 * CH, q + 7 * CH};
  uint4* pw = q + 8 * CH;
  uint4* pwih0h = pw;              uint4* pwih0l = pwih0h + CW0;
  uint4* pwhh0h = pwih0l + CW0;    uint4* pwhh0l = pwhh0h + CW;
  uint4* pwih1h = pwhh0l + CW;     uint4* pwih1l = pwih1h + CW;
  uint4* pwhh1h = pwih1l + CW;     uint4* pwhh1l = pwhh1h + CW;
  u16* embh = (u16*)(pwhh1l + CW);
  u16* embl = embh + VOCAB * EMB;
  int* prev = (int*)(embl + VOCAB * EMB);
  int* is_end = prev + BATCH;
  int* lengths = is_end + BATCH;
  u32* keys = (u32*)(lengths + BATCH);
  // total ~105 MB

  int* out_tok = (int*)d_out;
  int* len_out = out_tok + (size_t)BATCH * (MAXLEN + 1);

  init_kernel<<<dim3((BATCH * HID) / 256), 256, 0, stream>>>(
      prevs, c0, c1, (u16*)ph0hi[0], (u16*)ph0lo[0], (u16*)ph0hi[1],
      (u16*)ph0lo[1], (u16*)ph1hi[0], (u16*)ph1lo[0], (u16*)ph1hi[1],
      (u16*)ph1lo[1], prev, is_end, lengths, keys, out_tok);

  split_kernel<<<dim3((VOCAB * EMB + 255) / 256), 256, 0, stream>>>(
      emb, embh, embl, VOCAB * EMB);
  pack_w<<<dim3((int)((CW0 + 255) / 256)), 256, 0, stream>>>(
      Wih0, EMB, 2, pwih0h, pwih0l, (int)CW0);
  pack_w<<<dim3((int)((CW + 255) / 256)), 256, 0, stream>>>(
      Whh0, HID, NKT_H, pwhh0h, pwhh0l, (int)CW);
  pack_w<<<dim3((int)((CW + 255) / 256)), 256, 0, stream>>>(
      Wih1, HID, NKT_H, pwih1h, pwih1l, (int)CW);
  pack_w<<<dim3((int)((CW + 255) / 256)), 256, 0, stream>>>(
      Whh1, HID, NKT_H, pwhh1h, pwhh1l, (int)CW);

  int p = 0;
  for (int t = 0; t < MAXLEN; ++t) {
    lstm_mfma<true, false><<<dim3(256), 512, 0, stream>>>(
        nullptr, nullptr, embh, embl, prev, 2, ph0hi[p], ph0lo[p],
        pwih0h, pwih0l, pwhh0h, pwhh0l, bih0, bhh0, c0, nullptr,
        ph0hi[p ^ 1], ph0lo[p ^ 1]);
    lstm_mfma<false, true><<<dim3(256), 512, 0, stream>>>(
        ph0hi[p ^ 1], ph0lo[p ^ 1], nullptr, nullptr, nullptr, NKT_H,
        ph1hi[p], ph1lo[p], pwih1h, pwih1l, pwhh1h, pwhh1l, bih1, bhh1,
        c1, h1f, ph1hi[p ^ 1], ph1lo[p ^ 1]);
    sample_kernel<<<dim3(BATCH / 4), 256, 0, stream>>>(
        h1f, Wout, bout, keys, t, prev, is_end, lengths, out_tok,
        (t == MAXLEN - 1) ? len_out : nullptr);
    p ^= 1;
  }
  (void)in_sizes; (void)n_in; (void)out_size; (void)ws_size;
}